// Round 3
// baseline (82.247 us; speedup 1.0000x reference)
//
#include <hip/hip_runtime.h>

// LightConv: B=8, T=1024, H=8, S=64, K=31, C=512
// out[b,t,h*S+s] = sum_k softmax_k(filters[b,t,h,:])[k] * x[b, t+k-15, h*S+s] + bias[h*S+s]
// All tensors fp32 (per reference). fp32 accumulation.

#define BB 8
#define TDIM 1024
#define HH 8
#define SS 64
#define KK 31
#define CC (HH * SS)   // 512
#define HK (HH * KK)   // 248
#define TTILE 64
#define WIN 96         // rows t0-15 .. t0+80; last rows feed only the zero tap 31
#define PAD 15

__global__ __launch_bounds__(256, 2)
void lightconv_kernel(const float* __restrict__ xg,
                      const float* __restrict__ fg,
                      const float* __restrict__ bg,
                      float* __restrict__ og)
{
    __shared__ float xs[WIN * SS];      // 24576 B: x window, [row][ch]
    __shared__ float ws[TTILE][32];     // 8192 B: softmaxed weights, [t_local][k], ws[.][31]=0

    const int t0  = blockIdx.x * TTILE;
    const int h   = blockIdx.y;
    const int b   = blockIdx.z;
    const int tid = threadIdx.x;

    // ---- stage x window into LDS, zero outside [0,T) ----
    {
        const float* xb = xg + ((size_t)b * TDIM) * CC + h * SS;
        #pragma unroll
        for (int i = 0; i < 6; ++i) {
            int f  = tid + i * 256;        // quad index 0..1535
            int r  = f >> 4;               // window row 0..95
            int c4 = (f & 15) << 2;        // channel 0..60 step 4
            int t  = t0 - PAD + r;
            float4 v = make_float4(0.f, 0.f, 0.f, 0.f);
            if ((unsigned)t < (unsigned)TDIM)
                v = *reinterpret_cast<const float4*>(xb + (size_t)t * CC + c4);
            *reinterpret_cast<float4*>(&xs[r * SS + c4]) = v;
        }
    }

    // ---- softmax over K for this (b, h, t-tile): one thread per t row ----
    if (tid < TTILE) {
        const float* fp = fg + (size_t)(b * TDIM + t0 + tid) * HK + h * KK;
        float v[KK];
        float m = -1e30f;
        #pragma unroll
        for (int k = 0; k < KK; ++k) { v[k] = fp[k]; m = fmaxf(m, v[k]); }
        float s = 0.f;
        #pragma unroll
        for (int k = 0; k < KK; ++k) { v[k] = __expf(v[k] - m); s += v[k]; }
        float inv = 1.f / s;
        #pragma unroll
        for (int k = 0; k < KK; ++k) ws[tid][k] = v[k] * inv;
        ws[tid][KK] = 0.f;                // zero tap so we can run 8 full k-quads
    }
    __syncthreads();

    // ---- compute: thread owns 4 consecutive t x 4 consecutive channels ----
    const int sq = (tid & 15) << 2;       // channel offset in head: 0..60
    const int tb = (tid >> 4) << 2;       // local t base: 0..60

    // register sliding window: rows tb .. tb+34 of this thread's channel quad
    float4 xw[35];
    #pragma unroll
    for (int j = 0; j < 35; ++j)
        xw[j] = *reinterpret_cast<const float4*>(&xs[(tb + j) * SS + sq]);

    float4 bias4 = *reinterpret_cast<const float4*>(bg + h * SS + sq);

    float4 acc[4];
    #pragma unroll
    for (int tt = 0; tt < 4; ++tt) acc[tt] = bias4;

    #pragma unroll
    for (int tt = 0; tt < 4; ++tt) {
        #pragma unroll
        for (int kq = 0; kq < 8; ++kq) {
            float4 w4 = *reinterpret_cast<const float4*>(&ws[tb + tt][kq << 2]);
            const float* wv = &w4.x;
            #pragma unroll
            for (int m = 0; m < 4; ++m) {
                float w = wv[m];
                float4 xv = xw[tt + (kq << 2) + m];
                acc[tt].x = fmaf(w, xv.x, acc[tt].x);
                acc[tt].y = fmaf(w, xv.y, acc[tt].y);
                acc[tt].z = fmaf(w, xv.z, acc[tt].z);
                acc[tt].w = fmaf(w, xv.w, acc[tt].w);
            }
        }
    }

    // ---- store fp32 ----
    float* ob = og + (size_t)(b * TDIM + t0) * CC + h * SS;
    #pragma unroll
    for (int tt = 0; tt < 4; ++tt)
        *reinterpret_cast<float4*>(ob + (size_t)(tb + tt) * CC + sq) = acc[tt];
}

extern "C" void kernel_launch(void* const* d_in, const int* in_sizes, int n_in,
                              void* d_out, int out_size, void* d_ws, size_t ws_size,
                              hipStream_t stream)
{
    const float* x    = (const float*)d_in[0];
    const float* f    = (const float*)d_in[1];
    const float* bias = (const float*)d_in[2];
    float* out        = (float*)d_out;
    dim3 grid(TDIM / TTILE, HH, BB);   // 16 x 8 x 8 = 1024 blocks
    lightconv_kernel<<<grid, 256, 0, stream>>>(x, f, bias, out);
}

// Round 4
// 81.547 us; speedup vs baseline: 1.0086x; 1.0086x over previous
//
#include <hip/hip_runtime.h>

// LightConv: B=8, T=1024, H=8, S=64, K=31, C=512 (all fp32)
// out[b,t,h*S+s] = sum_k softmax_k(filters[b,t,h,:])[k] * x[b, t+k-15, h*S+s] + bias[h*S+s]

#define BB 8
#define TDIM 1024
#define HH 8
#define SS 64
#define KK 31
#define CC (HH * SS)   // 512
#define HK (HH * KK)   // 248
#define TTILE 64
#define WIN 96         // rows t0-15 .. t0+80
#define PAD 15
#define WSTRIDE 36     // ws row stride: 144 B -> consecutive rows hit disjoint bank quads

__global__ __launch_bounds__(256, 2)
void lightconv_kernel(const float* __restrict__ xg,
                      const float* __restrict__ fg,
                      const float* __restrict__ bg,
                      float* __restrict__ og)
{
    __shared__ float xs[WIN * SS];          // 24576 B: x window [row][ch]
    __shared__ float ws[TTILE * WSTRIDE];   // 9216 B: softmaxed weights, ws[r][31]=0

    const int t0  = blockIdx.x * TTILE;
    const int h   = blockIdx.y;
    const int b   = blockIdx.z;
    const int tid = threadIdx.x;

    const float* xb = xg + ((size_t)b * TDIM) * CC + h * SS;

    // ---- stage x window (96 rows x 64 ch) into LDS ----
    // interior blocks: async global->LDS DMA, no VGPR round-trip.
    // lane mapping: quad f = tid + i*256; LDS byte addr = f*16 = wave-uniform base + lane*16  (contract OK)
    if (blockIdx.x != 0 && blockIdx.x != (TDIM / TTILE - 1)) {
        #pragma unroll
        for (int i = 0; i < 6; ++i) {
            int f  = tid + i * 256;        // quad 0..1535
            int r  = f >> 4;               // row 0..95
            int c4 = (f & 15) << 2;        // ch 0..60
            const float* gp = xb + (size_t)(t0 - PAD + r) * CC + c4;
            __builtin_amdgcn_global_load_lds(
                (const __attribute__((address_space(1))) void*)gp,
                (__attribute__((address_space(3))) void*)&xs[f << 2],
                16, 0, 0);
        }
    } else {
        #pragma unroll
        for (int i = 0; i < 6; ++i) {
            int f  = tid + i * 256;
            int r  = f >> 4;
            int c4 = (f & 15) << 2;
            int t  = t0 - PAD + r;
            float4 v = make_float4(0.f, 0.f, 0.f, 0.f);
            if ((unsigned)t < (unsigned)TDIM)
                v = *reinterpret_cast<const float4*>(xb + (size_t)t * CC + c4);
            *reinterpret_cast<float4*>(&xs[f << 2]) = v;
        }
    }

    // ---- softmax over K, all 256 threads: 4 threads per t-row, width-4 shuffle reduce ----
    {
        const int row  = tid >> 2;         // 0..63
        const int q    = tid & 3;
        const int base = q * 8;            // taps base..base+7 (q=3: 24..30 + zero tap 31)
        const float* fp = fg + (size_t)(b * TDIM + t0 + row) * HK + h * KK + base;
        float v[8];
        #pragma unroll
        for (int j = 0; j < 8; ++j)
            v[j] = (base + j < KK) ? fp[j] : -1e30f;
        float m = v[0];
        #pragma unroll
        for (int j = 1; j < 8; ++j) m = fmaxf(m, v[j]);
        m = fmaxf(m, __shfl_xor(m, 1, 4));
        m = fmaxf(m, __shfl_xor(m, 2, 4));
        float s = 0.f;
        #pragma unroll
        for (int j = 0; j < 8; ++j) { v[j] = __expf(v[j] - m); s += v[j]; }  // pad slot -> exp(-1e30)=0
        s += __shfl_xor(s, 1, 4);
        s += __shfl_xor(s, 2, 4);
        float inv = 1.f / s;
        #pragma unroll
        for (int j = 0; j < 8; ++j)
            if (base + j < 32)
                ws[row * WSTRIDE + base + j] = v[j] * inv;   // tap 31 gets exactly 0
    }
    __syncthreads();

    // ---- compute: thread owns 4 consecutive t x 4 consecutive channels ----
    const int sq = (tid & 15) << 2;       // channel offset in head: 0..60
    const int tb = (tid >> 4) << 2;       // local t base: 0..60

    float4 xw[35];                        // rows tb..tb+34 of this channel quad
    #pragma unroll
    for (int j = 0; j < 35; ++j)
        xw[j] = *reinterpret_cast<const float4*>(&xs[(tb + j) * SS + sq]);

    float4 bias4 = *reinterpret_cast<const float4*>(bg + h * SS + sq);

    float4 acc[4];
    #pragma unroll
    for (int tt = 0; tt < 4; ++tt) acc[tt] = bias4;

    #pragma unroll
    for (int tt = 0; tt < 4; ++tt) {
        #pragma unroll
        for (int kq = 0; kq < 8; ++kq) {
            float4 w4 = *reinterpret_cast<const float4*>(&ws[(tb + tt) * WSTRIDE + (kq << 2)]);
            const float* wv = &w4.x;
            #pragma unroll
            for (int m = 0; m < 4; ++m) {
                float w = wv[m];
                float4 xv = xw[tt + (kq << 2) + m];
                acc[tt].x = fmaf(w, xv.x, acc[tt].x);
                acc[tt].y = fmaf(w, xv.y, acc[tt].y);
                acc[tt].z = fmaf(w, xv.z, acc[tt].z);
                acc[tt].w = fmaf(w, xv.w, acc[tt].w);
            }
        }
    }

    // ---- store fp32 ----
    float* ob = og + (size_t)(b * TDIM + t0) * CC + h * SS;
    #pragma unroll
    for (int tt = 0; tt < 4; ++tt)
        *reinterpret_cast<float4*>(ob + (size_t)(tb + tt) * CC + sq) = acc[tt];
}

extern "C" void kernel_launch(void* const* d_in, const int* in_sizes, int n_in,
                              void* d_out, int out_size, void* d_ws, size_t ws_size,
                              hipStream_t stream)
{
    const float* x    = (const float*)d_in[0];
    const float* f    = (const float*)d_in[1];
    const float* bias = (const float*)d_in[2];
    float* out        = (float*)d_out;
    dim3 grid(TDIM / TTILE, HH, BB);   // 16 x 8 x 8 = 1024 blocks
    lightconv_kernel<<<grid, 256, 0, stream>>>(x, f, bias, out);
}